// Round 7
// baseline (513.628 us; speedup 1.0000x reference)
//
#include <hip/hip_runtime.h>
#include <hip/hip_bf16.h>
#include <stdint.h>

typedef __hip_bfloat16 bf16;
typedef __bf16 bf16x8 __attribute__((ext_vector_type(8)));
typedef float f32x4 __attribute__((ext_vector_type(4)));

#define MFMA16(a, b, c) __builtin_amdgcn_mfma_f32_16x16x32_bf16((a), (b), (c), 0, 0, 0)

__device__ __forceinline__ void gload_lds16(const void* g, void* l) {
    __builtin_amdgcn_global_load_lds((const __attribute__((address_space(1))) void*)g,
                                     (__attribute__((address_space(3))) void*)l, 16, 0, 0);
}

// ---------------------------------------------------------------- cast kernel
struct alignas(16) B8 { bf16 v[8]; };
struct alignas(8)  B4 { bf16 v[4]; };

__global__ __launch_bounds__(256) void cast_all_k(
    const float* __restrict__ x, const float* __restrict__ wqkv, const float* __restrict__ wout,
    bf16* __restrict__ xb, bf16* __restrict__ wqkvb, bf16* __restrict__ woutb) {
    const size_t NX = (size_t)2048 * 2048 / 8;
    const size_t NW = (size_t)3 * 2048 * 2048 / 8;
    size_t i = (size_t)blockIdx.x * 256 + threadIdx.x;
    const float* s; bf16* d;
    if (i < NX)            { s = x;    d = xb; }
    else if (i < NX + NW)  { s = wqkv; d = wqkvb; i -= NX; }
    else                   { s = wout; d = woutb; i -= NX + NW; }
    float4 a = ((const float4*)s)[2 * i];
    float4 b = ((const float4*)s)[2 * i + 1];
    B8 t;
    t.v[0] = __float2bfloat16(a.x); t.v[1] = __float2bfloat16(a.y);
    t.v[2] = __float2bfloat16(a.z); t.v[3] = __float2bfloat16(a.w);
    t.v[4] = __float2bfloat16(b.x); t.v[5] = __float2bfloat16(b.y);
    t.v[6] = __float2bfloat16(b.z); t.v[7] = __float2bfloat16(b.w);
    ((B8*)d)[i] = t;
}

// ---------------------------------------------------------------- GEMM (B^T)
// 2-phase pipelined: dbuf LDS, counted vmcnt, raw barriers. (unchanged, passing)
__global__ __launch_bounds__(256) void gemm_bt(
    const bf16* __restrict__ A, const bf16* __restrict__ B, float* __restrict__ C,
    int M, int N, int K) {
    __shared__ __align__(16) bf16 As[2][128 * 32];
    __shared__ __align__(16) bf16 Bs[2][128 * 32];
    const int t = threadIdx.x;
    const int lane = t & 63, w = t >> 6;
    const int wr = w >> 1, wc = w & 1;
    const int l15 = lane & 15, lg = lane >> 4;
    const int m0 = blockIdx.y * 128, n0 = blockIdx.x * 128;

    const int row = t >> 2, cb = t & 3;
    const int row1 = (t + 256) >> 2, cb1 = t & 3;

    f32x4 acc[4][4] = {};

#define G_STAGE(buf, k0)                                                        \
    do {                                                                        \
        gload_lds16(&A[(size_t)(m0 + row) * K + (k0) + cb * 8],                 \
                    &As[buf][t * 8]);                                           \
        gload_lds16(&B[(size_t)(n0 + row) * K + (k0) + cb * 8],                 \
                    &Bs[buf][t * 8]);                                           \
        gload_lds16(&A[(size_t)(m0 + row1) * K + (k0) + cb1 * 8],               \
                    &As[buf][(t + 256) * 8]);                                   \
        gload_lds16(&B[(size_t)(n0 + row1) * K + (k0) + cb1 * 8],               \
                    &Bs[buf][(t + 256) * 8]);                                   \
    } while (0)

    G_STAGE(0, 0);
    int cur = 0;
    for (int k0 = 0; k0 < K; k0 += 32) {
        const bool hn = (k0 + 32 < K);
        if (hn) {
            G_STAGE(cur ^ 1, k0 + 32);
            asm volatile("s_waitcnt vmcnt(4)" ::: "memory");
        } else {
            asm volatile("s_waitcnt vmcnt(0)" ::: "memory");
        }
        __builtin_amdgcn_s_barrier();
        __builtin_amdgcn_sched_barrier(0);

        bf16x8 af[4], bfr[4];
#pragma unroll
        for (int mi = 0; mi < 4; ++mi)
            af[mi] = *(const bf16x8*)&As[cur][(wr * 64 + mi * 16 + l15) * 32 + lg * 8];
#pragma unroll
        for (int ni = 0; ni < 4; ++ni)
            bfr[ni] = *(const bf16x8*)&Bs[cur][(wc * 64 + ni * 16 + l15) * 32 + lg * 8];
#pragma unroll
        for (int mi = 0; mi < 4; ++mi)
#pragma unroll
            for (int ni = 0; ni < 4; ++ni)
                acc[mi][ni] = MFMA16(af[mi], bfr[ni], acc[mi][ni]);
        __builtin_amdgcn_s_barrier();
        cur ^= 1;
    }
#undef G_STAGE

#pragma unroll
    for (int mi = 0; mi < 4; ++mi) {
        int r0 = m0 + wr * 64 + mi * 16 + lg * 4;
#pragma unroll
        for (int ni = 0; ni < 4; ++ni) {
            int c0 = n0 + wc * 64 + ni * 16 + l15;
#pragma unroll
            for (int j = 0; j < 4; ++j)
                C[(size_t)(r0 + j) * N + c0] = acc[mi][ni][j];
        }
    }
}

// ---------------------------------------------------------------- RMSNorm+RoPE
__global__ __launch_bounds__(128) void normrope_k(
    const float* __restrict__ qkv, bf16* __restrict__ qb, bf16* __restrict__ kb) {
    const int t = blockIdx.x, h = blockIdx.y, d = threadIdx.x;
    const float* base = qkv + (size_t)t * 6144;
    float q = base[h * 128 + d];
    float k = base[2048 + h * 128 + d];

    __shared__ float red[4];
    __shared__ float qn[128], kn[128];
    float sq = q * q, sk = k * k;
#pragma unroll
    for (int m = 1; m <= 32; m <<= 1) {
        sq += __shfl_xor(sq, m);
        sk += __shfl_xor(sk, m);
    }
    if ((d & 63) == 0) { red[(d >> 6) * 2] = sq; red[(d >> 6) * 2 + 1] = sk; }
    __syncthreads();
    float rq = rsqrtf((red[0] + red[2]) * (1.0f / 128.0f) + 1e-6f);
    float rk = rsqrtf((red[1] + red[3]) * (1.0f / 128.0f) + 1e-6f);
    qn[d] = q * rq;
    kn[d] = k * rk;
    __syncthreads();

    int j = d & 63;
    float c = 1.0f, s = 0.0f;
    if (j < 32) {
        float af = exp2f(-10.0f * (float)j / 31.0f);
        float theta = (float)t * af;
        sincosf(theta, &s, &c);
    }
    float oq, ok;
    if (d < 64) { oq =  qn[d] * c + qn[d + 64] * s;  ok =  kn[d] * c + kn[d + 64] * s; }
    else        { oq = -qn[d - 64] * s + qn[d] * c;  ok = -kn[d - 64] * s + kn[d] * c; }

    size_t oidx = ((size_t)h * 2048 + t) * 128 + d;
    qb[oidx] = __float2bfloat16(oq * 0.08838834764831845f);
    kb[oidx] = __float2bfloat16(ok);
}

// ---------------------------------------------------------------- V pack
// Packs V into per-head 32-key swizzled panels:
// vt2[h][tile][r=0..63][c=0..7] 16B chunks, where c' = c ^ (r&7),
// kc = c'>>1, dlow = c'&1, d = 2r+dlow: chunk = V[t0+kc*8 .. +8][d].
__global__ __launch_bounds__(256) void vtrans_k(
    const float* __restrict__ qkv, bf16* __restrict__ vt2) {
    __shared__ bf16 Ts[32][136];           // [t][d], padded
    const int tile = blockIdx.x, h = blockIdx.y, tid = threadIdx.x;
    const int t0 = tile * 32;
#pragma unroll
    for (int it = 0; it < 4; ++it) {
        int f = tid + it * 256;            // 0..1023 float4 slots
        int tl = f >> 5, dc = (f & 31) * 4;
        float4 v = *(const float4*)&qkv[(size_t)(t0 + tl) * 6144 + 4096 + h * 128 + dc];
        Ts[tl][dc + 0] = __float2bfloat16(v.x);
        Ts[tl][dc + 1] = __float2bfloat16(v.y);
        Ts[tl][dc + 2] = __float2bfloat16(v.z);
        Ts[tl][dc + 3] = __float2bfloat16(v.w);
    }
    __syncthreads();
    bf16* pan = vt2 + ((size_t)h * 64 + tile) * 4096;
#pragma unroll
    for (int it = 0; it < 2; ++it) {
        int g = tid + it * 256;            // 0..511 16B chunks
        int r = g >> 3, c = g & 7;
        int cp = c ^ (r & 7);
        int kc = cp >> 1, dlow = cp & 1;
        int d = r * 2 + dlow;
        B8 p;
#pragma unroll
        for (int i = 0; i < 8; ++i) p.v[i] = Ts[kc * 8 + i][d];
        *(B8*)&pan[g * 8] = p;
    }
}

// ---------------------------------------------------------------- attention
// Split-KV, per-wave-independent pipelines, ZERO barriers.
// Grid (cz=8, qt=32, h=16), active if cz <= qt>>2. 4 waves/block; wave w owns
// Q-rows [qt*64+w*16, +16) and loops 32-key tiles over [kstart, kend_w) with
// its OWN double-buffered K/V LDS (33 KB/wave) and counted vmcnt(16).
// Records: m[64]f32 | l[64]f32 | O[64][128]bf16 (16896 B) per (qt,h,cz).
__global__ __launch_bounds__(256) void attn_main_k(
    const bf16* __restrict__ qg, const bf16* __restrict__ kg,
    const bf16* __restrict__ vt2, char* __restrict__ part) {
    const int T = 2048, D = 128;
    const int cz = blockIdx.x, qt = blockIdx.y, h = blockIdx.z;
    if (cz > (qt >> 2)) return;
    const int qb0 = qt * 64;
    const int kstart = cz * 256;
    const int kend = min(kstart + 256, (qt + 1) * 64);

    // per-wave region: K0 @0, K1 @4096, V0 @8192, V1 @12288, P @16384 (16x36)
    __shared__ __align__(16) bf16 LDS[4][16960];

    const int t = threadIdx.x;
    const int lane = t & 63, w = t >> 6;
    const int l15 = lane & 15, lg = lane >> 4;

    bf16* Kw = &LDS[w][0];
    bf16* Vw = &LDS[w][8192];
    bf16* Pw = &LDS[w][16384];

    const int kend_w = min(kend, qb0 + w * 16 + 16);

    const size_t qoff = ((size_t)h * T + qb0 + w * 16 + l15) * D;
    bf16x8 qf[4];
#pragma unroll
    for (int ks = 0; ks < 4; ++ks)
        qf[ks] = *(const bf16x8*)&qg[qoff + ks * 32 + lg * 8];

    bf16x8 onesf;
#pragma unroll
    for (int i = 0; i < 8; ++i) onesf[i] = (__bf16)1.0f;

    const bf16* kbase = kg + (size_t)h * T * D;
    const bf16* vbase = vt2 + (size_t)h * 64 * 4096;

    f32x4 o[8] = {};
    float mrow[4] = {-1e30f, -1e30f, -1e30f, -1e30f};
    float lrow[4] = {0.f, 0.f, 0.f, 0.f};

    // stage one 32-key tile (16 gload_lds: 8 K + 8 V)
#define W_STAGE(buf, k0)                                                         \
    do {                                                                         \
        const bf16* kpan = kbase + (size_t)(k0) * 128;                           \
        const bf16* vpan = vbase + (size_t)((k0) >> 5) * 4096;                   \
        _Pragma("unroll")                                                        \
        for (int i = 0; i < 8; ++i) {                                            \
            int f = lane + i * 64;                                               \
            int krow = f >> 4, kc = f & 15;                                      \
            gload_lds16(&kpan[krow * 128 + ((kc ^ (krow & 15)) * 8)],            \
                        &Kw[(buf) * 4096 + f * 8]);                              \
            gload_lds16(&vpan[f * 8], &Vw[(buf) * 4096 + f * 8]);                \
        }                                                                        \
    } while (0)

    int cur = 0;
    W_STAGE(0, kstart);
    for (int k0 = kstart; k0 < kend_w; k0 += 32) {
        const bool hn = (k0 + 32 < kend_w);
        if (hn) {
            W_STAGE(cur ^ 1, k0 + 32);
            asm volatile("s_waitcnt vmcnt(16)" ::: "memory");
        } else {
            asm volatile("s_waitcnt vmcnt(0)" ::: "memory");
        }
        __builtin_amdgcn_sched_barrier(0);

        // --- S = Q K^T (scale folded into Q)
        f32x4 sc0 = {}, sc1 = {};
#pragma unroll
        for (int ks = 0; ks < 4; ++ks) {
            int c = ks * 4 + lg;
            bf16x8 kf0 = *(const bf16x8*)&Kw[cur * 4096 + l15 * 128 + ((c ^ l15) & 15) * 8];
            bf16x8 kf1 = *(const bf16x8*)&Kw[cur * 4096 + (16 + l15) * 128 + ((c ^ l15) & 15) * 8];
            sc0 = MFMA16(qf[ks], kf0, sc0);
            sc1 = MFMA16(qf[ks], kf1, sc1);
        }

        const bool needmask = (k0 + 31) > (qb0 + w * 16);
        const int qrow_base = qb0 + w * 16 + lg * 4;
        float fac[4];
        bool anyresc = false;
#pragma unroll
        for (int j = 0; j < 4; ++j) {
            float s0 = sc0[j], s1 = sc1[j];
            if (needmask) {
                int qrow = qrow_base + j;
                if (k0 + l15 > qrow)      s0 = -1e30f;
                if (k0 + 16 + l15 > qrow) s1 = -1e30f;
            }
            float tm = fmaxf(s0, s1);
            tm = fmaxf(tm, __shfl_xor(tm, 1));
            tm = fmaxf(tm, __shfl_xor(tm, 2));
            tm = fmaxf(tm, __shfl_xor(tm, 4));
            tm = fmaxf(tm, __shfl_xor(tm, 8));
            if (__all(tm <= mrow[j] + 6.0f)) {         // defer-max (T13)
                fac[j] = 1.0f;
            } else {
                float mnew = fmaxf(mrow[j], tm);
                fac[j] = __expf(mrow[j] - mnew);
                mrow[j] = mnew;
                anyresc = true;
            }
            float p0 = __expf(s0 - mrow[j]), p1 = __expf(s1 - mrow[j]);
            int prow = lg * 4 + j;
            Pw[prow * 36 + l15]      = __float2bfloat16(p0);
            Pw[prow * 36 + 16 + l15] = __float2bfloat16(p1);
        }

        if (anyresc) {
#pragma unroll
            for (int nd = 0; nd < 8; ++nd)
#pragma unroll
                for (int j = 0; j < 4; ++j) o[nd][j] *= fac[j];
        }

        // --- O += P V ; l-sum via ones-operand MFMA
        bf16x8 pf = *(const bf16x8*)&Pw[l15 * 36 + lg * 8];
        f32x4 lsum = {};
        lsum = MFMA16(pf, onesf, lsum);
#pragma unroll
        for (int nd = 0; nd < 8; ++nd) {
            int dd = nd * 16 + l15;
            int r = dd >> 1;
            int c = (((lg << 1) | (dd & 1)) ^ (r & 7));
            bf16x8 vf = *(const bf16x8*)&Vw[cur * 4096 + r * 64 + c * 8];
            o[nd] = MFMA16(pf, vf, o[nd]);
        }
#pragma unroll
        for (int j = 0; j < 4; ++j) lrow[j] = lrow[j] * fac[j] + lsum[j];
        cur ^= 1;
    }
#undef W_STAGE

    // --- write partial record (m,l fp32; O bf16)
    int B = qt >> 2, r4 = qt & 3;
    int slot = h * 144 + qt + 2 * B * (B - 1) + r4 * B + cz;
    char* rec = part + (size_t)slot * 16896;
    float* mrec = (float*)rec;
    float* lrec = (float*)(rec + 256);
    bf16*  orec = (bf16*)(rec + 512);
    if (l15 == 0) {
#pragma unroll
        for (int j = 0; j < 4; ++j) {
            mrec[w * 16 + lg * 4 + j] = mrow[j];
            lrec[w * 16 + lg * 4 + j] = lrow[j];
        }
    }
#pragma unroll
    for (int nd = 0; nd < 8; ++nd)
#pragma unroll
        for (int j = 0; j < 4; ++j)
            orec[(w * 16 + lg * 4 + j) * 128 + nd * 16 + l15] = __float2bfloat16(o[nd][j]);
}

// ---------------------------------------------------------------- merge
__global__ __launch_bounds__(256) void attn_merge_k(
    const char* __restrict__ part, bf16* __restrict__ y) {
    const int qt = blockIdx.x, h = blockIdx.y, tid = threadIdx.x;
    const int nch = (qt >> 2) + 1;
    int B = qt >> 2, r4 = qt & 3;
    const int base = h * 144 + qt + 2 * B * (B - 1) + r4 * B;
    const int r = tid >> 2;
    const int d0 = (tid & 3) * 32;

    float mi[8], li[8], wgt[8];
    float M = -1e30f;
#pragma unroll
    for (int i = 0; i < 8; ++i) {
        if (i < nch) {
            const char* rec = part + (size_t)(base + i) * 16896;
            mi[i] = ((const float*)rec)[r];
            li[i] = ((const float*)(rec + 256))[r];
            M = fmaxf(M, mi[i]);
        } else { mi[i] = -1e30f; li[i] = 0.f; }
    }
    float L = 0.f;
#pragma unroll
    for (int i = 0; i < 8; ++i) {
        wgt[i] = (i < nch) ? __expf(mi[i] - M) : 0.f;
        L += li[i] * wgt[i];
    }
    float invL = 1.0f / L;

    bf16* yrow = &y[(size_t)(qt * 64 + r) * 2048 + h * 128 + d0];
#pragma unroll
    for (int dd = 0; dd < 32; dd += 8) {
        float facc[8] = {};
#pragma unroll
        for (int i = 0; i < 8; ++i) {
            if (i < nch) {
                const bf16* orec = (const bf16*)(part + (size_t)(base + i) * 16896 + 512);
                B8 ov = *(const B8*)&orec[r * 128 + d0 + dd];
#pragma unroll
                for (int e = 0; e < 8; ++e)
                    facc[e] += wgt[i] * __bfloat162float(ov.v[e]);
            }
        }
        B8 p;
#pragma unroll
        for (int e = 0; e < 8; ++e) p.v[e] = __float2bfloat16(facc[e] * invL);
        *(B8*)&yrow[dd] = p;
    }
}

// ---------------------------------------------------------------- launch
extern "C" void kernel_launch(void* const* d_in, const int* in_sizes, int n_in,
                              void* d_out, int out_size, void* d_ws, size_t ws_size,
                              hipStream_t stream) {
    const float* x    = (const float*)d_in[0];
    const float* wqkv = (const float*)d_in[1];
    const float* wout = (const float*)d_in[2];
    float* out = (float*)d_out;

    char* ws = (char*)d_ws;
    bf16*  xb    = (bf16*)(ws);                         //  8,388,608
    bf16*  wqkvb = (bf16*)(ws + 8388608);               // 25,165,824
    bf16*  woutb = (bf16*)(ws + 33554432);              //  8,388,608
    float* qkvf  = (float*)(ws + 41943040);             // 50,331,648 (reused as `part`)
    bf16*  qb    = (bf16*)(ws + 92274688);              //  8,388,608
    bf16*  kb    = (bf16*)(ws + 100663296);             //  8,388,608
    bf16*  vt2   = (bf16*)(ws + 109051904);             //  8,388,608  [h][tile][panel]
    bf16*  yb    = (bf16*)(ws + 117440512);             //  8,388,608

    cast_all_k<<<10240, 256, 0, stream>>>(x, wqkv, wout, xb, wqkvb, woutb);
    gemm_bt<<<dim3(48, 16), 256, 0, stream>>>(xb, wqkvb, qkvf, 2048, 6144, 2048);
    normrope_k<<<dim3(2048, 16), 128, 0, stream>>>(qkvf, qb, kb);
    vtrans_k<<<dim3(64, 16), 256, 0, stream>>>(qkvf, vt2);
    attn_main_k<<<dim3(8, 32, 16), 256, 0, stream>>>(qb, kb, vt2, (char*)qkvf);
    attn_merge_k<<<dim3(32, 16), 256, 0, stream>>>((const char*)qkvf, yb);
    gemm_bt<<<dim3(16, 16), 256, 0, stream>>>(yb, woutb, out, 2048, 2048, 2048);
}

// Round 8
// 354.606 us; speedup vs baseline: 1.4484x; 1.4484x over previous
//
#include <hip/hip_runtime.h>
#include <hip/hip_bf16.h>
#include <stdint.h>

typedef __hip_bfloat16 bf16;
typedef __bf16 bf16x8 __attribute__((ext_vector_type(8)));
typedef float f32x4 __attribute__((ext_vector_type(4)));

#define MFMA16(a, b, c) __builtin_amdgcn_mfma_f32_16x16x32_bf16((a), (b), (c), 0, 0, 0)

__device__ __forceinline__ void gload_lds16(const void* g, void* l) {
    __builtin_amdgcn_global_load_lds((const __attribute__((address_space(1))) void*)g,
                                     (__attribute__((address_space(3))) void*)l, 16, 0, 0);
}

// ---------------------------------------------------------------- cast kernel
struct alignas(16) B8 { bf16 v[8]; };
struct alignas(8)  B4 { bf16 v[4]; };

__global__ __launch_bounds__(256) void cast_all_k(
    const float* __restrict__ x, const float* __restrict__ wqkv, const float* __restrict__ wout,
    bf16* __restrict__ xb, bf16* __restrict__ wqkvb, bf16* __restrict__ woutb) {
    const size_t NX = (size_t)2048 * 2048 / 8;
    const size_t NW = (size_t)3 * 2048 * 2048 / 8;
    size_t i = (size_t)blockIdx.x * 256 + threadIdx.x;
    const float* s; bf16* d;
    if (i < NX)            { s = x;    d = xb; }
    else if (i < NX + NW)  { s = wqkv; d = wqkvb; i -= NX; }
    else                   { s = wout; d = woutb; i -= NX + NW; }
    float4 a = ((const float4*)s)[2 * i];
    float4 b = ((const float4*)s)[2 * i + 1];
    B8 t;
    t.v[0] = __float2bfloat16(a.x); t.v[1] = __float2bfloat16(a.y);
    t.v[2] = __float2bfloat16(a.z); t.v[3] = __float2bfloat16(a.w);
    t.v[4] = __float2bfloat16(b.x); t.v[5] = __float2bfloat16(b.y);
    t.v[6] = __float2bfloat16(b.z); t.v[7] = __float2bfloat16(b.w);
    ((B8*)d)[i] = t;
}

// ---------------------------------------------------------------- GEMM1: 256x192 tile, 8 waves, BK=64
// C[m][n] = sum_k A[m][k]*B[n][k]. M=2048, N=6144, K=2048. Grid = 256 blocks (full chip).
// 2-phase counted-vmcnt pipeline, T2 chunk-XOR swizzle, XCD-bijective block swizzle.
__global__ __launch_bounds__(512, 2) void gemm256_bt(
    const bf16* __restrict__ A, const bf16* __restrict__ B, float* __restrict__ C) {
    const int K = 2048, N = 6144;
    __shared__ __align__(16) bf16 As[2][256 * 64];   // 64 KB
    __shared__ __align__(16) bf16 Bs[2][192 * 64];   // 48 KB

    const int t = threadIdx.x;
    const int lane = t & 63, w = t >> 6;
    const int wm = w >> 2, wn = w & 3;               // 2M x 4N waves
    const int l15 = lane & 15, lg = lane >> 4;

    const int bid = blockIdx.x;                      // 256 blocks, 256%8==0
    const int swz = (bid & 7) * 32 + (bid >> 3);     // XCD swizzle (bijective)
    const int m0 = (swz >> 5) * 256;                 // 8 M-tiles
    const int n0 = (swz & 31) * 192;                 // 32 N-tiles

    f32x4 acc[8][3] = {};

    // staging: A 2048 chunks (4/thread), B 1536 chunks (3/thread); 7 loads/thread
#define S256(buf, k0)                                                            \
    do {                                                                         \
        _Pragma("unroll")                                                        \
        for (int i = 0; i < 4; ++i) {                                            \
            int f = t + i * 512;                                                 \
            int r = f >> 3, c = f & 7;                                           \
            gload_lds16(&A[(size_t)(m0 + r) * K + (k0) + ((c ^ (r & 7)) * 8)],   \
                        &As[buf][f * 8]);                                        \
        }                                                                        \
        _Pragma("unroll")                                                        \
        for (int i = 0; i < 3; ++i) {                                            \
            int f = t + i * 512;                                                 \
            int r = f >> 3, c = f & 7;                                           \
            gload_lds16(&B[(size_t)(n0 + r) * K + (k0) + ((c ^ (r & 7)) * 8)],   \
                        &Bs[buf][f * 8]);                                        \
        }                                                                        \
    } while (0)

    S256(0, 0);
    int cur = 0;
    for (int k0 = 0; k0 < K; k0 += 64) {
        if (k0 + 64 < K) {
            S256(cur ^ 1, k0 + 64);
            asm volatile("s_waitcnt vmcnt(7)" ::: "memory");
        } else {
            asm volatile("s_waitcnt vmcnt(0)" ::: "memory");
        }
        __builtin_amdgcn_s_barrier();
        __builtin_amdgcn_sched_barrier(0);

#pragma unroll
        for (int kk = 0; kk < 2; ++kk) {
            bf16x8 bfr[3];
#pragma unroll
            for (int ni = 0; ni < 3; ++ni) {
                int row = wn * 48 + ni * 16 + l15;
                int c = (kk * 4 + lg) ^ (row & 7);
                bfr[ni] = *(const bf16x8*)&Bs[cur][row * 64 + c * 8];
            }
#pragma unroll
            for (int mi = 0; mi < 8; ++mi) {
                int row = wm * 128 + mi * 16 + l15;
                int c = (kk * 4 + lg) ^ (row & 7);
                bf16x8 af = *(const bf16x8*)&As[cur][row * 64 + c * 8];
#pragma unroll
                for (int ni = 0; ni < 3; ++ni)
                    acc[mi][ni] = MFMA16(af, bfr[ni], acc[mi][ni]);
            }
        }
        __builtin_amdgcn_s_barrier();
        cur ^= 1;
    }
#undef S256

#pragma unroll
    for (int mi = 0; mi < 8; ++mi) {
        int r0 = m0 + wm * 128 + mi * 16 + lg * 4;
#pragma unroll
        for (int ni = 0; ni < 3; ++ni) {
            int c0 = n0 + wn * 48 + ni * 16 + l15;
#pragma unroll
            for (int j = 0; j < 4; ++j)
                C[(size_t)(r0 + j) * N + c0] = acc[mi][ni][j];
        }
    }
}

// ---------------------------------------------------------------- GEMM (B^T) 128², used for GEMM2
__global__ __launch_bounds__(256) void gemm_bt(
    const bf16* __restrict__ A, const bf16* __restrict__ B, float* __restrict__ C,
    int M, int N, int K) {
    __shared__ __align__(16) bf16 As[2][128 * 32];
    __shared__ __align__(16) bf16 Bs[2][128 * 32];
    const int t = threadIdx.x;
    const int lane = t & 63, w = t >> 6;
    const int wr = w >> 1, wc = w & 1;
    const int l15 = lane & 15, lg = lane >> 4;
    const int m0 = blockIdx.y * 128, n0 = blockIdx.x * 128;

    const int row = t >> 2, cb = t & 3;
    const int row1 = (t + 256) >> 2, cb1 = t & 3;

    f32x4 acc[4][4] = {};

#define G_STAGE(buf, k0)                                                        \
    do {                                                                        \
        gload_lds16(&A[(size_t)(m0 + row) * K + (k0) + cb * 8],                 \
                    &As[buf][t * 8]);                                           \
        gload_lds16(&B[(size_t)(n0 + row) * K + (k0) + cb * 8],                 \
                    &Bs[buf][t * 8]);                                           \
        gload_lds16(&A[(size_t)(m0 + row1) * K + (k0) + cb1 * 8],               \
                    &As[buf][(t + 256) * 8]);                                   \
        gload_lds16(&B[(size_t)(n0 + row1) * K + (k0) + cb1 * 8],               \
                    &Bs[buf][(t + 256) * 8]);                                   \
    } while (0)

    G_STAGE(0, 0);
    int cur = 0;
    for (int k0 = 0; k0 < K; k0 += 32) {
        const bool hn = (k0 + 32 < K);
        if (hn) {
            G_STAGE(cur ^ 1, k0 + 32);
            asm volatile("s_waitcnt vmcnt(4)" ::: "memory");
        } else {
            asm volatile("s_waitcnt vmcnt(0)" ::: "memory");
        }
        __builtin_amdgcn_s_barrier();
        __builtin_amdgcn_sched_barrier(0);

        bf16x8 af[4], bfr[4];
#pragma unroll
        for (int mi = 0; mi < 4; ++mi)
            af[mi] = *(const bf16x8*)&As[cur][(wr * 64 + mi * 16 + l15) * 32 + lg * 8];
#pragma unroll
        for (int ni = 0; ni < 4; ++ni)
            bfr[ni] = *(const bf16x8*)&Bs[cur][(wc * 64 + ni * 16 + l15) * 32 + lg * 8];
#pragma unroll
        for (int mi = 0; mi < 4; ++mi)
#pragma unroll
            for (int ni = 0; ni < 4; ++ni)
                acc[mi][ni] = MFMA16(af[mi], bfr[ni], acc[mi][ni]);
        __builtin_amdgcn_s_barrier();
        cur ^= 1;
    }
#undef G_STAGE

#pragma unroll
    for (int mi = 0; mi < 4; ++mi) {
        int r0 = m0 + wr * 64 + mi * 16 + lg * 4;
#pragma unroll
        for (int ni = 0; ni < 4; ++ni) {
            int c0 = n0 + wc * 64 + ni * 16 + l15;
#pragma unroll
            for (int j = 0; j < 4; ++j)
                C[(size_t)(r0 + j) * N + c0] = acc[mi][ni][j];
        }
    }
}

// ---------------------------------------------------------------- RMSNorm+RoPE
__global__ __launch_bounds__(128) void normrope_k(
    const float* __restrict__ qkv, bf16* __restrict__ qb, bf16* __restrict__ kb) {
    const int t = blockIdx.x, h = blockIdx.y, d = threadIdx.x;
    const float* base = qkv + (size_t)t * 6144;
    float q = base[h * 128 + d];
    float k = base[2048 + h * 128 + d];

    __shared__ float red[4];
    __shared__ float qn[128], kn[128];
    float sq = q * q, sk = k * k;
#pragma unroll
    for (int m = 1; m <= 32; m <<= 1) {
        sq += __shfl_xor(sq, m);
        sk += __shfl_xor(sk, m);
    }
    if ((d & 63) == 0) { red[(d >> 6) * 2] = sq; red[(d >> 6) * 2 + 1] = sk; }
    __syncthreads();
    float rq = rsqrtf((red[0] + red[2]) * (1.0f / 128.0f) + 1e-6f);
    float rk = rsqrtf((red[1] + red[3]) * (1.0f / 128.0f) + 1e-6f);
    qn[d] = q * rq;
    kn[d] = k * rk;
    __syncthreads();

    int j = d & 63;
    float c = 1.0f, s = 0.0f;
    if (j < 32) {
        float af = exp2f(-10.0f * (float)j / 31.0f);
        float theta = (float)t * af;
        sincosf(theta, &s, &c);
    }
    float oq, ok;
    if (d < 64) { oq =  qn[d] * c + qn[d + 64] * s;  ok =  kn[d] * c + kn[d + 64] * s; }
    else        { oq = -qn[d - 64] * s + qn[d] * c;  ok = -kn[d - 64] * s + kn[d] * c; }

    size_t oidx = ((size_t)h * 2048 + t) * 128 + d;
    qb[oidx] = __float2bfloat16(oq * 0.08838834764831845f);
    kb[oidx] = __float2bfloat16(ok);
}

// ---------------------------------------------------------------- V transpose (r5 version)
__global__ __launch_bounds__(256) void vtrans_k(
    const float* __restrict__ qkv, bf16* __restrict__ vt) {
    __shared__ bf16 Ts[64][72];
    const int t0 = blockIdx.x * 64, d0 = blockIdx.y * 64, h = blockIdx.z;
    const int tid = threadIdx.x;
#pragma unroll
    for (int it = 0; it < 4; ++it) {
        int f = tid + it * 256;
        int tl = f >> 4, dl = (f & 15) * 4;
        float4 v = *(const float4*)&qkv[(size_t)(t0 + tl) * 6144 + 4096 + h * 128 + d0 + dl];
        Ts[tl][dl + 0] = __float2bfloat16(v.x);
        Ts[tl][dl + 1] = __float2bfloat16(v.y);
        Ts[tl][dl + 2] = __float2bfloat16(v.z);
        Ts[tl][dl + 3] = __float2bfloat16(v.w);
    }
    __syncthreads();
#pragma unroll
    for (int it = 0; it < 2; ++it) {
        int f = tid + it * 256;
        int dl = f >> 3, tc = f & 7;
        B8 p;
#pragma unroll
        for (int i = 0; i < 8; ++i) p.v[i] = Ts[tc * 8 + i][dl];
        *(B8*)&vt[((size_t)h * 128 + d0 + dl) * 2048 + t0 + tc * 8] = p;
    }
}

// ---------------------------------------------------------------- attention (r5 version: split-KV chunk=256, block-staged)
__global__ __launch_bounds__(256) void attn_main_k(
    const bf16* __restrict__ qg, const bf16* __restrict__ kg,
    const bf16* __restrict__ vt, char* __restrict__ part) {
    const int T = 2048, D = 128;
    const int cz = blockIdx.x, qt = blockIdx.y, h = blockIdx.z;
    if (cz > (qt >> 2)) return;
    const int qb0 = qt * 64;
    const int kstart = cz * 256;
    const int kend = min(kstart + 256, (qt + 1) * 64);

    __shared__ __align__(16) bf16 Ks[64 * 128];
    __shared__ __align__(16) bf16 Vs[128 * 64];
    __shared__ __align__(16) bf16 Ps[4][16 * 64];

    const int t = threadIdx.x;
    const int lane = t & 63, w = t >> 6;
    const int l15 = lane & 15, lg = lane >> 4;

    const size_t qoff = ((size_t)h * T + qb0 + w * 16 + l15) * D;
    bf16x8 qf[4];
#pragma unroll
    for (int ks = 0; ks < 4; ++ks)
        qf[ks] = *(const bf16x8*)&qg[qoff + ks * 32 + lg * 8];

    bf16x8 onesf;
#pragma unroll
    for (int i = 0; i < 8; ++i) onesf[i] = (__bf16)1.0f;

    f32x4 o[8] = {};
    float mrow[4] = {-1e30f, -1e30f, -1e30f, -1e30f};
    float lrow[4] = {0.f, 0.f, 0.f, 0.f};

    for (int k0 = kstart; k0 < kend; k0 += 64) {
#pragma unroll
        for (int c = 0; c < 4; ++c) {
            int f = t + c * 256;
            int krow = f >> 4, kc = f & 15;
            gload_lds16(&kg[((size_t)h * T + k0 + krow) * D + ((kc ^ (krow & 15)) * 8)],
                        &Ks[f * 8]);
            int dr = f >> 3, vc = f & 7;
            gload_lds16(&vt[((size_t)h * D + dr) * T + k0 + ((vc ^ (dr & 7)) * 8)],
                        &Vs[f * 8]);
        }
        __syncthreads();

        f32x4 sc[4] = {};
#pragma unroll
        for (int ks = 0; ks < 4; ++ks) {
#pragma unroll
            for (int nb = 0; nb < 4; ++nb) {
                int key = nb * 16 + l15;
                int c = ks * 4 + lg;
                bf16x8 kf = *(const bf16x8*)&Ks[key * 128 + ((c ^ (key & 15)) * 8)];
                sc[nb] = MFMA16(qf[ks], kf, sc[nb]);
            }
        }

        const bool diag = (k0 == qb0);
        const int qrow_base = qb0 + w * 16 + lg * 4;
        float fac[4];
        bool anyresc = false;
#pragma unroll
        for (int j = 0; j < 4; ++j) {
            float s0 = sc[0][j], s1 = sc[1][j], s2 = sc[2][j], s3 = sc[3][j];
            if (diag) {
                int qrow = qrow_base + j;
                if (k0 + l15 > qrow)      s0 = -1e30f;
                if (k0 + 16 + l15 > qrow) s1 = -1e30f;
                if (k0 + 32 + l15 > qrow) s2 = -1e30f;
                if (k0 + 48 + l15 > qrow) s3 = -1e30f;
            }
            float tm = fmaxf(fmaxf(s0, s1), fmaxf(s2, s3));
            tm = fmaxf(tm, __shfl_xor(tm, 1));
            tm = fmaxf(tm, __shfl_xor(tm, 2));
            tm = fmaxf(tm, __shfl_xor(tm, 4));
            tm = fmaxf(tm, __shfl_xor(tm, 8));
            if (__all(tm <= mrow[j] + 6.0f)) {
                fac[j] = 1.0f;
            } else {
                float mnew = fmaxf(mrow[j], tm);
                fac[j] = __expf(mrow[j] - mnew);
                mrow[j] = mnew;
                anyresc = true;
            }
            float p0 = __expf(s0 - mrow[j]), p1 = __expf(s1 - mrow[j]);
            float p2 = __expf(s2 - mrow[j]), p3 = __expf(s3 - mrow[j]);
            int prow = lg * 4 + j;
            int sub = l15 & 7, hi = l15 >> 3;
            bf16* pw = &Ps[w][prow * 64 + sub];
            pw[(((0 + hi) ^ (prow & 7)) * 8)] = __float2bfloat16(p0);
            pw[(((2 + hi) ^ (prow & 7)) * 8)] = __float2bfloat16(p1);
            pw[(((4 + hi) ^ (prow & 7)) * 8)] = __float2bfloat16(p2);
            pw[(((6 + hi) ^ (prow & 7)) * 8)] = __float2bfloat16(p3);
        }

        if (anyresc) {
#pragma unroll
            for (int nd = 0; nd < 8; ++nd)
#pragma unroll
                for (int j = 0; j < 4; ++j) o[nd][j] *= fac[j];
        }

        f32x4 lsum = {};
#pragma unroll
        for (int hk = 0; hk < 2; ++hk) {
            bf16x8 pf = *(const bf16x8*)&Ps[w][l15 * 64 + (((hk * 4 + lg) ^ (l15 & 7)) * 8)];
            lsum = MFMA16(pf, onesf, lsum);
#pragma unroll
            for (int nd = 0; nd < 8; ++nd) {
                int dd = nd * 16 + l15;
                bf16x8 vf = *(const bf16x8*)&Vs[dd * 64 + (((hk * 4 + lg) ^ (dd & 7)) * 8)];
                o[nd] = MFMA16(pf, vf, o[nd]);
            }
        }
#pragma unroll
        for (int j = 0; j < 4; ++j) lrow[j] = lrow[j] * fac[j] + lsum[j];
        __syncthreads();
    }

    int B = qt >> 2, r4 = qt & 3;
    int slot = h * 144 + qt + 2 * B * (B - 1) + r4 * B + cz;
    char* rec = part + (size_t)slot * 16896;
    float* mrec = (float*)rec;
    float* lrec = (float*)(rec + 256);
    bf16*  orec = (bf16*)(rec + 512);
    if (l15 == 0) {
#pragma unroll
        for (int j = 0; j < 4; ++j) {
            mrec[w * 16 + lg * 4 + j] = mrow[j];
            lrec[w * 16 + lg * 4 + j] = lrow[j];
        }
    }
#pragma unroll
    for (int nd = 0; nd < 8; ++nd)
#pragma unroll
        for (int j = 0; j < 4; ++j)
            orec[(w * 16 + lg * 4 + j) * 128 + nd * 16 + l15] = __float2bfloat16(o[nd][j]);
}

// ---------------------------------------------------------------- merge
__global__ __launch_bounds__(256) void attn_merge_k(
    const char* __restrict__ part, bf16* __restrict__ y) {
    const int qt = blockIdx.x, h = blockIdx.y, tid = threadIdx.x;
    const int nch = (qt >> 2) + 1;
    int B = qt >> 2, r4 = qt & 3;
    const int base = h * 144 + qt + 2 * B * (B - 1) + r4 * B;
    const int r = tid >> 2;
    const int d0 = (tid & 3) * 32;

    float mi[8], li[8], wgt[8];
    float M = -1e30f;
#pragma unroll
    for (int i = 0; i < 8; ++i) {
        if (i < nch) {
            const char* rec = part + (size_t)(base + i) * 16896;
            mi[i] = ((const float*)rec)[r];
            li[i] = ((const float*)(rec + 256))[r];
            M = fmaxf(M, mi[i]);
        } else { mi[i] = -1e30f; li[i] = 0.f; }
    }
    float L = 0.f;
#pragma unroll
    for (int i = 0; i < 8; ++i) {
        wgt[i] = (i < nch) ? __expf(mi[i] - M) : 0.f;
        L += li[i] * wgt[i];
    }
    float invL = 1.0f / L;

    bf16* yrow = &y[(size_t)(qt * 64 + r) * 2048 + h * 128 + d0];
#pragma unroll
    for (int dd = 0; dd < 32; dd += 8) {
        float facc[8] = {};
#pragma unroll
        for (int i = 0; i < 8; ++i) {
            if (i < nch) {
                const bf16* orec = (const bf16*)(part + (size_t)(base + i) * 16896 + 512);
                B8 ov = *(const B8*)&orec[r * 128 + d0 + dd];
#pragma unroll
                for (int e = 0; e < 8; ++e)
                    facc[e] += wgt[i] * __bfloat162float(ov.v[e]);
            }
        }
        B8 p;
#pragma unroll
        for (int e = 0; e < 8; ++e) p.v[e] = __float2bfloat16(facc[e] * invL);
        *(B8*)&yrow[dd] = p;
    }
}

// ---------------------------------------------------------------- launch
extern "C" void kernel_launch(void* const* d_in, const int* in_sizes, int n_in,
                              void* d_out, int out_size, void* d_ws, size_t ws_size,
                              hipStream_t stream) {
    const float* x    = (const float*)d_in[0];
    const float* wqkv = (const float*)d_in[1];
    const float* wout = (const float*)d_in[2];
    float* out = (float*)d_out;

    char* ws = (char*)d_ws;
    bf16*  xb    = (bf16*)(ws);                         //  8,388,608
    bf16*  wqkvb = (bf16*)(ws + 8388608);               // 25,165,824
    bf16*  woutb = (bf16*)(ws + 33554432);              //  8,388,608
    float* qkvf  = (float*)(ws + 41943040);             // 50,331,648 (reused as `part`)
    bf16*  qb    = (bf16*)(ws + 92274688);              //  8,388,608
    bf16*  kb    = (bf16*)(ws + 100663296);             //  8,388,608
    bf16*  vt    = (bf16*)(ws + 109051904);             //  8,388,608  [h][d][t]
    bf16*  yb    = (bf16*)(ws + 117440512);             //  8,388,608

    cast_all_k<<<10240, 256, 0, stream>>>(x, wqkv, wout, xb, wqkvb, woutb);
    gemm256_bt<<<256, 512, 0, stream>>>(xb, wqkvb, qkvf);
    normrope_k<<<dim3(2048, 16), 128, 0, stream>>>(qkvf, qb, kb);
    vtrans_k<<<dim3(32, 2, 16), 256, 0, stream>>>(qkvf, vt);
    attn_main_k<<<dim3(8, 32, 16), 256, 0, stream>>>(qb, kb, vt, (char*)qkvf);
    attn_merge_k<<<dim3(32, 16), 256, 0, stream>>>((const char*)qkvf, yb);
    gemm_bt<<<dim3(16, 16), 256, 0, stream>>>(yb, woutb, out, 2048, 2048, 2048);
}

// Round 10
// 323.629 us; speedup vs baseline: 1.5871x; 1.0957x over previous
//
#include <hip/hip_runtime.h>
#include <hip/hip_bf16.h>
#include <stdint.h>

typedef __hip_bfloat16 bf16;
typedef __bf16 bf16x8 __attribute__((ext_vector_type(8)));
typedef float f32x4 __attribute__((ext_vector_type(4)));

#define MFMA16(a, b, c) __builtin_amdgcn_mfma_f32_16x16x32_bf16((a), (b), (c), 0, 0, 0)

__device__ __forceinline__ void gload_lds16(const void* g, void* l) {
    __builtin_amdgcn_global_load_lds((const __attribute__((address_space(1))) void*)g,
                                     (__attribute__((address_space(3))) void*)l, 16, 0, 0);
}

// ---------------------------------------------------------------- cast kernel
struct alignas(16) B8 { bf16 v[8]; };
struct alignas(8)  B4 { bf16 v[4]; };

__global__ __launch_bounds__(256) void cast_all_k(
    const float* __restrict__ x, const float* __restrict__ wqkv, const float* __restrict__ wout,
    bf16* __restrict__ xb, bf16* __restrict__ wqkvb, bf16* __restrict__ woutb) {
    const size_t NX = (size_t)2048 * 2048 / 8;
    const size_t NW = (size_t)3 * 2048 * 2048 / 8;
    size_t i = (size_t)blockIdx.x * 256 + threadIdx.x;
    const float* s; bf16* d;
    if (i < NX)            { s = x;    d = xb; }
    else if (i < NX + NW)  { s = wqkv; d = wqkvb; i -= NX; }
    else                   { s = wout; d = woutb; i -= NX + NW; }
    float4 a = ((const float4*)s)[2 * i];
    float4 b = ((const float4*)s)[2 * i + 1];
    B8 t;
    t.v[0] = __float2bfloat16(a.x); t.v[1] = __float2bfloat16(a.y);
    t.v[2] = __float2bfloat16(a.z); t.v[3] = __float2bfloat16(a.w);
    t.v[4] = __float2bfloat16(b.x); t.v[5] = __float2bfloat16(b.y);
    t.v[6] = __float2bfloat16(b.z); t.v[7] = __float2bfloat16(b.w);
    ((B8*)d)[i] = t;
}

// ---------------------------------------------------------------- GEMM1: 256x192 tile, 8 waves, BK=64
__global__ __launch_bounds__(512) void gemm256_bt(
    const bf16* __restrict__ A, const bf16* __restrict__ B, float* __restrict__ C) {
    const int K = 2048, N = 6144;
    __shared__ __align__(16) bf16 As[2][256 * 64];   // 64 KB
    __shared__ __align__(16) bf16 Bs[2][192 * 64];   // 48 KB

    const int t = threadIdx.x;
    const int lane = t & 63, w = t >> 6;
    const int wm = w >> 2, wn = w & 3;               // 2M x 4N waves
    const int l15 = lane & 15, lg = lane >> 4;

    const int bid = blockIdx.x;                      // 256 blocks, 256%8==0
    const int swz = (bid & 7) * 32 + (bid >> 3);     // XCD swizzle (bijective)
    const int m0 = (swz >> 5) * 256;
    const int n0 = (swz & 31) * 192;

    f32x4 acc[8][3] = {};

#define S256(buf, k0)                                                            \
    do {                                                                         \
        _Pragma("unroll")                                                        \
        for (int i = 0; i < 4; ++i) {                                            \
            int f = t + i * 512;                                                 \
            int r = f >> 3, c = f & 7;                                           \
            gload_lds16(&A[(size_t)(m0 + r) * K + (k0) + ((c ^ (r & 7)) * 8)],   \
                        &As[buf][f * 8]);                                        \
        }                                                                        \
        _Pragma("unroll")                                                        \
        for (int i = 0; i < 3; ++i) {                                            \
            int f = t + i * 512;                                                 \
            int r = f >> 3, c = f & 7;                                           \
            gload_lds16(&B[(size_t)(n0 + r) * K + (k0) + ((c ^ (r & 7)) * 8)],   \
                        &Bs[buf][f * 8]);                                        \
        }                                                                        \
    } while (0)

    S256(0, 0);
    int cur = 0;
    for (int k0 = 0; k0 < K; k0 += 64) {
        if (k0 + 64 < K) {
            S256(cur ^ 1, k0 + 64);
            asm volatile("s_waitcnt vmcnt(7)" ::: "memory");
        } else {
            asm volatile("s_waitcnt vmcnt(0)" ::: "memory");
        }
        __builtin_amdgcn_s_barrier();
        __builtin_amdgcn_sched_barrier(0);

#pragma unroll
        for (int kk = 0; kk < 2; ++kk) {
            bf16x8 bfr[3];
#pragma unroll
            for (int ni = 0; ni < 3; ++ni) {
                int row = wn * 48 + ni * 16 + l15;
                int c = (kk * 4 + lg) ^ (row & 7);
                bfr[ni] = *(const bf16x8*)&Bs[cur][row * 64 + c * 8];
            }
#pragma unroll
            for (int mi = 0; mi < 8; ++mi) {
                int row = wm * 128 + mi * 16 + l15;
                int c = (kk * 4 + lg) ^ (row & 7);
                bf16x8 af = *(const bf16x8*)&As[cur][row * 64 + c * 8];
#pragma unroll
                for (int ni = 0; ni < 3; ++ni)
                    acc[mi][ni] = MFMA16(af, bfr[ni], acc[mi][ni]);
            }
        }
        __builtin_amdgcn_s_barrier();
        cur ^= 1;
    }
#undef S256

#pragma unroll
    for (int mi = 0; mi < 8; ++mi) {
        int r0 = m0 + wm * 128 + mi * 16 + lg * 4;
#pragma unroll
        for (int ni = 0; ni < 3; ++ni) {
            int c0 = n0 + wn * 48 + ni * 16 + l15;
#pragma unroll
            for (int j = 0; j < 4; ++j)
                C[(size_t)(r0 + j) * N + c0] = acc[mi][ni][j];
        }
    }
}

// ---------------------------------------------------------------- GEMM (B^T) 128², used for GEMM2
__global__ __launch_bounds__(256) void gemm_bt(
    const bf16* __restrict__ A, const bf16* __restrict__ B, float* __restrict__ C,
    int M, int N, int K) {
    __shared__ __align__(16) bf16 As[2][128 * 32];
    __shared__ __align__(16) bf16 Bs[2][128 * 32];
    const int t = threadIdx.x;
    const int lane = t & 63, w = t >> 6;
    const int wr = w >> 1, wc = w & 1;
    const int l15 = lane & 15, lg = lane >> 4;
    const int m0 = blockIdx.y * 128, n0 = blockIdx.x * 128;

    const int row = t >> 2, cb = t & 3;
    const int row1 = (t + 256) >> 2, cb1 = t & 3;

    f32x4 acc[4][4] = {};

#define G_STAGE(buf, k0)                                                        \
    do {                                                                        \
        gload_lds16(&A[(size_t)(m0 + row) * K + (k0) + cb * 8],                 \
                    &As[buf][t * 8]);                                           \
        gload_lds16(&B[(size_t)(n0 + row) * K + (k0) + cb * 8],                 \
                    &Bs[buf][t * 8]);                                           \
        gload_lds16(&A[(size_t)(m0 + row1) * K + (k0) + cb1 * 8],               \
                    &As[buf][(t + 256) * 8]);                                   \
        gload_lds16(&B[(size_t)(n0 + row1) * K + (k0) + cb1 * 8],               \
                    &Bs[buf][(t + 256) * 8]);                                   \
    } while (0)

    G_STAGE(0, 0);
    int cur = 0;
    for (int k0 = 0; k0 < K; k0 += 32) {
        const bool hn = (k0 + 32 < K);
        if (hn) {
            G_STAGE(cur ^ 1, k0 + 32);
            asm volatile("s_waitcnt vmcnt(4)" ::: "memory");
        } else {
            asm volatile("s_waitcnt vmcnt(0)" ::: "memory");
        }
        __builtin_amdgcn_s_barrier();
        __builtin_amdgcn_sched_barrier(0);

        bf16x8 af[4], bfr[4];
#pragma unroll
        for (int mi = 0; mi < 4; ++mi)
            af[mi] = *(const bf16x8*)&As[cur][(wr * 64 + mi * 16 + l15) * 32 + lg * 8];
#pragma unroll
        for (int ni = 0; ni < 4; ++ni)
            bfr[ni] = *(const bf16x8*)&Bs[cur][(wc * 64 + ni * 16 + l15) * 32 + lg * 8];
#pragma unroll
        for (int mi = 0; mi < 4; ++mi)
#pragma unroll
            for (int ni = 0; ni < 4; ++ni)
                acc[mi][ni] = MFMA16(af[mi], bfr[ni], acc[mi][ni]);
        __builtin_amdgcn_s_barrier();
        cur ^= 1;
    }
#undef G_STAGE

#pragma unroll
    for (int mi = 0; mi < 4; ++mi) {
        int r0 = m0 + wr * 64 + mi * 16 + lg * 4;
#pragma unroll
        for (int ni = 0; ni < 4; ++ni) {
            int c0 = n0 + wc * 64 + ni * 16 + l15;
#pragma unroll
            for (int j = 0; j < 4; ++j)
                C[(size_t)(r0 + j) * N + c0] = acc[mi][ni][j];
        }
    }
}

// ---------------------------------------------------------------- RMSNorm+RoPE
__global__ __launch_bounds__(128) void normrope_k(
    const float* __restrict__ qkv, bf16* __restrict__ qb, bf16* __restrict__ kb) {
    const int t = blockIdx.x, h = blockIdx.y, d = threadIdx.x;
    const float* base = qkv + (size_t)t * 6144;
    float q = base[h * 128 + d];
    float k = base[2048 + h * 128 + d];

    __shared__ float red[4];
    __shared__ float qn[128], kn[128];
    float sq = q * q, sk = k * k;
#pragma unroll
    for (int m = 1; m <= 32; m <<= 1) {
        sq += __shfl_xor(sq, m);
        sk += __shfl_xor(sk, m);
    }
    if ((d & 63) == 0) { red[(d >> 6) * 2] = sq; red[(d >> 6) * 2 + 1] = sk; }
    __syncthreads();
    float rq = rsqrtf((red[0] + red[2]) * (1.0f / 128.0f) + 1e-6f);
    float rk = rsqrtf((red[1] + red[3]) * (1.0f / 128.0f) + 1e-6f);
    qn[d] = q * rq;
    kn[d] = k * rk;
    __syncthreads();

    int j = d & 63;
    float c = 1.0f, s = 0.0f;
    if (j < 32) {
        float af = exp2f(-10.0f * (float)j / 31.0f);
        float theta = (float)t * af;
        sincosf(theta, &s, &c);
    }
    float oq, ok;
    if (d < 64) { oq =  qn[d] * c + qn[d + 64] * s;  ok =  kn[d] * c + kn[d + 64] * s; }
    else        { oq = -qn[d - 64] * s + qn[d] * c;  ok = -kn[d - 64] * s + kn[d] * c; }

    size_t oidx = ((size_t)h * 2048 + t) * 128 + d;
    qb[oidx] = __float2bfloat16(oq * 0.08838834764831845f);
    kb[oidx] = __float2bfloat16(ok);
}

// ---------------------------------------------------------------- V transpose
__global__ __launch_bounds__(256) void vtrans_k(
    const float* __restrict__ qkv, bf16* __restrict__ vt) {
    __shared__ bf16 Ts[64][72];
    const int t0 = blockIdx.x * 64, d0 = blockIdx.y * 64, h = blockIdx.z;
    const int tid = threadIdx.x;
#pragma unroll
    for (int it = 0; it < 4; ++it) {
        int f = tid + it * 256;
        int tl = f >> 4, dl = (f & 15) * 4;
        float4 v = *(const float4*)&qkv[(size_t)(t0 + tl) * 6144 + 4096 + h * 128 + d0 + dl];
        Ts[tl][dl + 0] = __float2bfloat16(v.x);
        Ts[tl][dl + 1] = __float2bfloat16(v.y);
        Ts[tl][dl + 2] = __float2bfloat16(v.z);
        Ts[tl][dl + 3] = __float2bfloat16(v.w);
    }
    __syncthreads();
#pragma unroll
    for (int it = 0; it < 2; ++it) {
        int f = tid + it * 256;
        int dl = f >> 3, tc = f & 7;
        B8 p;
#pragma unroll
        for (int i = 0; i < 8; ++i) p.v[i] = Ts[tc * 8 + i][dl];
        *(B8*)&vt[((size_t)h * 128 + d0 + dl) * 2048 + t0 + tc * 8] = p;
    }
}

// ---------------------------------------------------------------- attention
// Split-KV chunk=256, block-staged (r5 skeleton) + FIXED-MAX softmax:
// scores are bounded: |q_eff|<=1 (rms-norm + 1/sqrt(D) folded), |k|<=sqrt(128)
// => s <= 11.6 < 12. p = exp(s-12), no max tracking, no rescale, no shuffles.
// Records: l[64]f32 | O[64][128]bf16 (16640 B) per (qt,h,cz); merge = plain sum.
__global__ __launch_bounds__(256) void attn_main_k(
    const bf16* __restrict__ qg, const bf16* __restrict__ kg,
    const bf16* __restrict__ vt, char* __restrict__ part) {
    const int T = 2048, D = 128;
    const int cz = blockIdx.x, qt = blockIdx.y, h = blockIdx.z;
    if (cz > (qt >> 2)) return;
    const int qb0 = qt * 64;
    const int kstart = cz * 256;
    const int kend = min(kstart + 256, (qt + 1) * 64);

    __shared__ __align__(16) bf16 Ks[64 * 128];
    __shared__ __align__(16) bf16 Vs[128 * 64];
    __shared__ __align__(16) bf16 Ps[4][16 * 64];

    const int t = threadIdx.x;
    const int lane = t & 63, w = t >> 6;
    const int l15 = lane & 15, lg = lane >> 4;

    const size_t qoff = ((size_t)h * T + qb0 + w * 16 + l15) * D;
    bf16x8 qf[4];
#pragma unroll
    for (int ks = 0; ks < 4; ++ks)
        qf[ks] = *(const bf16x8*)&qg[qoff + ks * 32 + lg * 8];

    bf16x8 onesf;
#pragma unroll
    for (int i = 0; i < 8; ++i) onesf[i] = (__bf16)1.0f;

    f32x4 o[8] = {};
    f32x4 lrow = {0.f, 0.f, 0.f, 0.f};

    for (int k0 = kstart; k0 < kend; k0 += 64) {
#pragma unroll
        for (int c = 0; c < 4; ++c) {
            int f = t + c * 256;
            int krow = f >> 4, kc = f & 15;
            gload_lds16(&kg[((size_t)h * T + k0 + krow) * D + ((kc ^ (krow & 15)) * 8)],
                        &Ks[f * 8]);
            int dr = f >> 3, vc = f & 7;
            gload_lds16(&vt[((size_t)h * D + dr) * T + k0 + ((vc ^ (dr & 7)) * 8)],
                        &Vs[f * 8]);
        }
        __syncthreads();

        f32x4 sc[4] = {};
#pragma unroll
        for (int ks = 0; ks < 4; ++ks) {
#pragma unroll
            for (int nb = 0; nb < 4; ++nb) {
                int key = nb * 16 + l15;
                int c = ks * 4 + lg;
                bf16x8 kf = *(const bf16x8*)&Ks[key * 128 + ((c ^ (key & 15)) * 8)];
                sc[nb] = MFMA16(qf[ks], kf, sc[nb]);
            }
        }

        const bool diag = (k0 == qb0);
        const int qrow_base = qb0 + w * 16 + lg * 4;
#pragma unroll
        for (int j = 0; j < 4; ++j) {
            float s0 = sc[0][j], s1 = sc[1][j], s2 = sc[2][j], s3 = sc[3][j];
            if (diag) {
                int qrow = qrow_base + j;
                if (k0 + l15 > qrow)      s0 = -1e30f;
                if (k0 + 16 + l15 > qrow) s1 = -1e30f;
                if (k0 + 32 + l15 > qrow) s2 = -1e30f;
                if (k0 + 48 + l15 > qrow) s3 = -1e30f;
            }
            // fixed-max softmax: p = exp(s - 12), bounded (0, 0.6]
            float p0 = __expf(s0 - 12.0f), p1 = __expf(s1 - 12.0f);
            float p2 = __expf(s2 - 12.0f), p3 = __expf(s3 - 12.0f);
            int prow = lg * 4 + j;
            int sub = l15 & 7, hi = l15 >> 3;
            bf16* pw = &Ps[w][prow * 64 + sub];
            pw[(((0 + hi) ^ (prow & 7)) * 8)] = __float2bfloat16(p0);
            pw[(((2 + hi) ^ (prow & 7)) * 8)] = __float2bfloat16(p1);
            pw[(((4 + hi) ^ (prow & 7)) * 8)] = __float2bfloat16(p2);
            pw[(((6 + hi) ^ (prow & 7)) * 8)] = __float2bfloat16(p3);
        }

        f32x4 lsum = {};
#pragma unroll
        for (int hk = 0; hk < 2; ++hk) {
            bf16x8 pf = *(const bf16x8*)&Ps[w][l15 * 64 + (((hk * 4 + lg) ^ (l15 & 7)) * 8)];
            lsum = MFMA16(pf, onesf, lsum);
#pragma unroll
            for (int nd = 0; nd < 8; ++nd) {
                int dd = nd * 16 + l15;
                bf16x8 vf = *(const bf16x8*)&Vs[dd * 64 + (((hk * 4 + lg) ^ (dd & 7)) * 8)];
                o[nd] = MFMA16(pf, vf, o[nd]);
            }
        }
#pragma unroll
        for (int j = 0; j < 4; ++j) lrow[j] += lsum[j];
        __syncthreads();
    }

    // --- write partial record (l fp32; O bf16)
    int B = qt >> 2, r4 = qt & 3;
    int slot = h * 144 + qt + 2 * B * (B - 1) + r4 * B + cz;
    char* rec = part + (size_t)slot * 16640;
    float* lrec = (float*)rec;
    bf16*  orec = (bf16*)(rec + 256);
    if (l15 == 0) {
#pragma unroll
        for (int j = 0; j < 4; ++j)
            lrec[w * 16 + lg * 4 + j] = lrow[j];
    }
#pragma unroll
    for (int nd = 0; nd < 8; ++nd)
#pragma unroll
        for (int j = 0; j < 4; ++j)
            orec[(w * 16 + lg * 4 + j) * 128 + nd * 16 + l15] = __float2bfloat16(o[nd][j]);
}

// ---------------------------------------------------------------- merge (plain sums, shared max)
__global__ __launch_bounds__(256) void attn_merge_k(
    const char* __restrict__ part, bf16* __restrict__ y) {
    const int qt = blockIdx.x, h = blockIdx.y, tid = threadIdx.x;
    const int nch = (qt >> 2) + 1;
    int B = qt >> 2, r4 = qt & 3;
    const int base = h * 144 + qt + 2 * B * (B - 1) + r4 * B;
    const int r = tid >> 2;
    const int d0 = (tid & 3) * 32;

    float L = 0.f;
#pragma unroll
    for (int i = 0; i < 8; ++i)
        if (i < nch)
            L += ((const float*)(part + (size_t)(base + i) * 16640))[r];
    float invL = 1.0f / L;

    bf16* yrow = &y[(size_t)(qt * 64 + r) * 2048 + h * 128 + d0];
#pragma unroll
    for (int dd = 0; dd < 32; dd += 8) {
        float facc[8] = {};
#pragma unroll
        for (int i = 0; i < 8; ++i) {
            if (i < nch) {
                const bf16* orec = (const bf16*)(part + (size_t)(base + i) * 16640 + 256);
                B8 ov = *(const B8*)&orec[r * 128 + d0 + dd];
#pragma unroll
                for (int e = 0; e < 8; ++e)
                    facc[e] += __bfloat162float(ov.v[e]);
            }
        }
        B8 p;
#pragma unroll
        for (int e = 0; e < 8; ++e) p.v[e] = __float2bfloat16(facc[e] * invL);
        *(B8*)&yrow[dd] = p;
    }
}

// ---------------------------------------------------------------- launch
extern "C" void kernel_launch(void* const* d_in, const int* in_sizes, int n_in,
                              void* d_out, int out_size, void* d_ws, size_t ws_size,
                              hipStream_t stream) {
    const float* x    = (const float*)d_in[0];
    const float* wqkv = (const float*)d_in[1];
    const float* wout = (const float*)d_in[2];
    float* out = (float*)d_out;

    char* ws = (char*)d_ws;
    bf16*  xb    = (bf16*)(ws);                         //  8,388,608
    bf16*  wqkvb = (bf16*)(ws + 8388608);               // 25,165,824
    bf16*  woutb = (bf16*)(ws + 33554432);              //  8,388,608
    float* qkvf  = (float*)(ws + 41943040);             // 50,331,648 (reused as `part`)
    bf16*  qb    = (bf16*)(ws + 92274688);              //  8,388,608
    bf16*  kb    = (bf16*)(ws + 100663296);             //  8,388,608
    bf16*  vt    = (bf16*)(ws + 109051904);             //  8,388,608  [h][d][t]
    bf16*  yb    = (bf16*)(ws + 117440512);             //  8,388,608

    cast_all_k<<<10240, 256, 0, stream>>>(x, wqkv, wout, xb, wqkvb, woutb);
    gemm256_bt<<<256, 512, 0, stream>>>(xb, wqkvb, qkvf);
    normrope_k<<<dim3(2048, 16), 128, 0, stream>>>(qkvf, qb, kb);
    vtrans_k<<<dim3(32, 2, 16), 256, 0, stream>>>(qkvf, vt);
    attn_main_k<<<dim3(8, 32, 16), 256, 0, stream>>>(qb, kb, vt, (char*)qkvf);
    attn_merge_k<<<dim3(32, 16), 256, 0, stream>>>((const char*)qkvf, yb);
    gemm_bt<<<dim3(16, 16), 256, 0, stream>>>(yb, woutb, out, 2048, 2048, 2048);
}